// Round 2
// baseline (537.776 us; speedup 1.0000x reference)
//
#include <hip/hip_runtime.h>
#include <math.h>

// Problem dims (fixed by reference setup_inputs):
//   video [B=8, C=1024, T=64, W=14, H=14] fp32 ; mu/sigma [N=3] fp32
//   out   [B, C*N] fp32, out[b, c*3+n] = (1/T) * sum_{t,w,h} video[b,c,t,w,h]*f[n,w,h]
#define B_    8
#define C_    1024
#define T_    64
#define W_    14
#define H_    14
#define N_    3
#define WH    (W_ * H_)     // 196 floats per frame
#define WH4   (WH / 4)      // 49 float4 per frame
#define SLAB4 (T_ * WH4)    // 3136 float4 per (b,c) slab (50 KB)

// One wave per (b,c). The wave streams its slab LINEARLY: iteration i, lane l
// loads float4 #(i*64+l) -- all 64 lanes active, 1 KiB contiguous per
// instruction. The in-frame weight index p = (i*64+l) mod 49 advances by
// +15 (mod 49) per iteration; weights come from a 2.3 KB LDS copy of the
// normalized filters (3x ds_read_b128 per iter, offsets n*784 B).
__global__ __launch_bounds__(256) void attn_pool_kernel(
    const float* __restrict__ video,
    const float* __restrict__ mu_x,
    const float* __restrict__ mu_y,
    const float* __restrict__ sigma_x,
    const float* __restrict__ sigma_y,
    float* __restrict__ out)
{
    __shared__ float4 fw4[N_][WH4];   // normalized filters, float4 granularity

    const int tid  = threadIdx.x;
    const int wave = tid >> 6;
    const int lane = tid & 63;

    // ---- Phase 1: threads 0..48 compute raw (unnormalized) filter float4 ----
    if (tid < WH4) {
#pragma unroll
        for (int n = 0; n < N_; ++n) {
            // squash params exactly as reference
            const float mux  = 6.5f * (tanhf(mu_x[n]) + 1.0f);   // (W-1)*(tanh+1)/2
            const float muy  = 6.5f * (tanhf(mu_y[n]) + 1.0f);
            const float sgx  = 1.0f / (1.0f + expf(-sigma_x[n]));
            const float sgy  = 1.0f / (1.0f + expf(-sigma_y[n]));
            // sx^2 = exp(2*(1.5 - 2*sig)) = exp(3 - 4*sig)
            const float invx = 1.0f / (expf(3.0f - 4.0f * sgx) + 1e-6f);
            const float invy = 1.0f / (expf(3.0f - 4.0f * sgy) + 1e-6f);
            float fj[4];
#pragma unroll
            for (int j = 0; j < 4; ++j) {
                const int   wh = 4 * tid + j;
                const int   w  = wh / H_;
                const int   h  = wh - w * H_;
                const float dx = (float)w - mux;
                const float dy = (float)h - muy;
                fj[j] = expf(-0.5f * (dx * dx * invx + dy * dy * invy));
            }
            fw4[n][tid] = make_float4(fj[0], fj[1], fj[2], fj[3]);
        }
    }
    __syncthreads();

    // ---- Phase 2: wave 0 normalizes the filters in LDS ----
    if (wave == 0) {
#pragma unroll
        for (int n = 0; n < N_; ++n) {
            float s = 0.0f;
            float4 v;
            if (lane < WH4) {
                v = fw4[n][lane];
                s = v.x + v.y + v.z + v.w;
            }
#pragma unroll
            for (int off = 32; off > 0; off >>= 1) s += __shfl_xor(s, off);
            const float inv = 1.0f / (s + 1e-6f);
            if (lane < WH4) {
                v.x *= inv; v.y *= inv; v.z *= inv; v.w *= inv;
                fw4[n][lane] = v;
            }
        }
    }
    __syncthreads();

    // ---- Phase 3: stream the slab, all 64 lanes active ----
    const int bc = blockIdx.x * 4 + wave;                 // [0, B_*C_)
    const float4* v4 = (const float4*)video + (size_t)bc * SLAB4;

    // initial in-frame float4 position for i=0: lane mod 49
    int p = (lane < WH4) ? lane : lane - WH4;
    float a0 = 0.0f, a1 = 0.0f, a2 = 0.0f;

#pragma unroll 7
    for (int i = 0; i < SLAB4 / 64; ++i) {                // 49 iterations
        const float4 v  = v4[i * 64 + lane];
        const float4 w0 = fw4[0][p];
        const float4 w1 = fw4[1][p];
        const float4 w2 = fw4[2][p];
        a0 += v.x * w0.x + v.y * w0.y + v.z * w0.z + v.w * w0.w;
        a1 += v.x * w1.x + v.y * w1.y + v.z * w1.z + v.w * w1.w;
        a2 += v.x * w2.x + v.y * w2.y + v.z * w2.z + v.w * w2.w;
        p += 15;                     // (p + 64) mod 49
        if (p >= WH4) p -= WH4;
    }

    // ---- wave-reduce the 3 accumulators ----
#pragma unroll
    for (int off = 32; off > 0; off >>= 1) {
        a0 += __shfl_xor(a0, off);
        a1 += __shfl_xor(a1, off);
        a2 += __shfl_xor(a2, off);
    }
    if (lane == 0) {
        float* o = out + (size_t)bc * N_;   // b*C*N + c*N == bc*N
        o[0] = a0 * (1.0f / T_);
        o[1] = a1 * (1.0f / T_);
        o[2] = a2 * (1.0f / T_);
    }
}

extern "C" void kernel_launch(void* const* d_in, const int* in_sizes, int n_in,
                              void* d_out, int out_size, void* d_ws, size_t ws_size,
                              hipStream_t stream) {
    const float* video   = (const float*)d_in[0];
    const float* mu_x    = (const float*)d_in[1];
    const float* mu_y    = (const float*)d_in[2];
    const float* sigma_x = (const float*)d_in[3];
    const float* sigma_y = (const float*)d_in[4];
    float* out = (float*)d_out;

    const int waves  = B_ * C_;        // 8192 (b,c) pairs, one wave each
    const int blocks = waves / 4;      // 4 waves per 256-thread block
    attn_pool_kernel<<<blocks, 256, 0, stream>>>(video, mu_x, mu_y,
                                                 sigma_x, sigma_y, out);
}